// Round 2
// baseline (1398.156 us; speedup 1.0000x reference)
//
#include <hip/hip_runtime.h>

#define NCH 128      // channels C
#define NGR 256      // graphs B
#define NBR 32       // branches K
#define NEG_SLOPE 0.01f

constexpr int CHUNK = 2048;            // nodes per block (phase 1)
constexpr int GWIN  = 2;               // graphs per LDS window (chunk spans <=2 graphs: ~7812 nodes/graph)
constexpr int SLOTS = GWIN * NBR;      // 64 local slots

__device__ inline float sel4(float4 v, int el) {
    float r = v.x;
    r = (el == 1) ? v.y : r;
    r = (el == 2) ? v.z : r;
    r = (el == 3) ? v.w : r;
    return r;
}

// fast-path inner loop; GUARD only for the ragged tail block
template <bool GUARD>
__device__ inline void accum_chunk(
    const float* __restrict__ node_embed,
    const unsigned short* __restrict__ sslot,
    float (*acc)[NCH],
    int s, int len, int t)
{
    const int r   = t >> 5;            // node row within 8-group
    const int c4  = t & 31;            // float4 channel group
    const int rot = (c4 >> 3) & 3;     // bank-conflict-free rotation (verified: 0 conflicts)

    for (int i0 = 0; i0 < CHUNK; i0 += 32) {
        int    sl[4];
        float4 v[4];
        #pragma unroll
        for (int u = 0; u < 4; ++u) {
            const int i = i0 + u * 8 + r;
            sl[u] = sslot[i];
            if (GUARD) {
                v[u] = make_float4(0.f, 0.f, 0.f, 0.f);
                if (i < len)
                    v[u] = ((const float4*)node_embed)[(size_t)(s + i) * (NCH / 4) + c4];
            } else {
                v[u] = ((const float4*)node_embed)[(size_t)(s + i) * (NCH / 4) + c4];
            }
        }
        #pragma unroll
        for (int u = 0; u < 4; ++u) {
            if (sl[u] != 0xFFFF) {
                float* dst = &acc[sl[u]][c4 * 4];
                #pragma unroll
                for (int j = 0; j < 4; ++j) {
                    const int el = (j + rot) & 3;
                    atomicAdd(&dst[el], sel4(v[u], el));
                }
            }
        }
    }
}

// -------- Phase 1: segment-sum into branch_embed[B*K][C] + per-graph branch max
__global__ __launch_bounds__(256) void scatter_kernel(
    const float* __restrict__ node_embed,   // [N, C]
    const int*   __restrict__ batch,        // [N] sorted
    const int*   __restrict__ branch,       // [N] in [0,K)
    float*       __restrict__ branch_embed, // [B*K, C], pre-zeroed
    int*         __restrict__ max_b,        // [B], pre-init very negative
    int n_nodes)
{
    __shared__ float          acc[SLOTS][NCH];  // 32 KB
    __shared__ unsigned short sslot[CHUNK];     // 4 KB packed slot ids
    __shared__ int            gmax[GWIN];
    __shared__ int            sflag;

    const int t = threadIdx.x;
    for (int i = t; i < SLOTS * NCH / 4; i += 256)
        ((float4*)acc)[i] = make_float4(0.f, 0.f, 0.f, 0.f);
    if (t == 0) sflag = 0;
    if (t < GWIN) gmax[t] = -1;
    __syncthreads();

    const int s    = blockIdx.x * CHUNK;
    const int len  = min(n_nodes - s, CHUNK);
    const int base = batch[s];                  // batch sorted -> window base

    // stage packed slot ids; detect window overflow (block-uniform, never in practice)
    for (int i = t; i < CHUNK; i += 256) {
        unsigned short m = 0xFFFFu;
        if (i < len) {
            const int g  = batch[s + i];
            const int br = branch[s + i];
            const int w  = g - base;
            if (w < GWIN) {
                m = (unsigned short)(w * NBR + br);
                atomicMax(&gmax[w], br);
            } else {
                atomicOr(&sflag, 1);
            }
        }
        sslot[i] = m;
    }
    __syncthreads();

    if (!sflag) {
        if (len == CHUNK) accum_chunk<false>(node_embed, sslot, acc, s, len, t);
        else              accum_chunk<true >(node_embed, sslot, acc, s, len, t);
    } else {
        // correctness fallback (window span > GWIN): direct global atomics
        const int r = t >> 5, c4 = t & 31;
        for (int i0 = 0; i0 < CHUNK; i0 += 8) {
            const int i = i0 + r;
            if (i < len) {
                const int n = s + i;
                const int g = batch[n], br = branch[n];
                const float4 v = ((const float4*)node_embed)[(size_t)n * (NCH / 4) + c4];
                float* dst = &branch_embed[((size_t)g * NBR + br) * NCH + c4 * 4];
                atomicAdd(&dst[0], v.x); atomicAdd(&dst[1], v.y);
                atomicAdd(&dst[2], v.z); atomicAdd(&dst[3], v.w);
                if (c4 == 0) atomicMax(&max_b[g], br);
            }
        }
    }
    __syncthreads();

    // flush LDS window to global (skip zeros to cut atomic traffic)
    const size_t gbase = (size_t)base * NBR * NCH;
    const size_t lim   = (size_t)NGR * NBR * NCH;
    for (int i = t; i < SLOTS * NCH; i += 256) {
        const float v = ((float*)acc)[i];
        if (v != 0.0f) {
            const size_t gi = gbase + (size_t)i;
            if (gi < lim) atomicAdd(&branch_embed[gi], v);
        }
    }
    if (t < GWIN) {
        const int g = base + t;
        if (g < NGR && gmax[t] >= 0) atomicMax(&max_b[g], gmax[t]);
    }
}

// -------- Phase 2: per-slot MLP + masked per-graph sum
__global__ __launch_bounds__(256) void mlp_kernel(
    const float* __restrict__ branch_embed, // [B*K, C]
    const int*   __restrict__ max_b,        // [B]
    const float* __restrict__ W1,           // [C, C] row-major
    const float* __restrict__ b1,           // [C]
    const float* __restrict__ W2,           // [C] (C x 1)
    const float* __restrict__ b2,           // [1]
    float*       __restrict__ out)          // [B]
{
    __shared__ float W1s[NCH * NCH];        // 64 KB
    __shared__ float b1s[NCH], W2s[NCH];
    __shared__ float rows[2][NCH];
    __shared__ float red[2][NCH];
    __shared__ float sval[NBR];

    const int t = threadIdx.x;
    const int b = blockIdx.x;

    for (int i = t; i < NCH * NCH / 4; i += 256)
        ((float4*)W1s)[i] = ((const float4*)W1)[i];
    if (t < NCH) { b1s[t] = b1[t]; W2s[t] = W2[t]; }
    __syncthreads();

    const int half = t >> 7;   // which of 2 slots this thread works on
    const int j    = t & 127;  // output channel

    for (int k0 = 0; k0 < NBR; k0 += 2) {
        const int slot = k0 + half;
        rows[half][j] = branch_embed[((size_t)b * NBR + slot) * NCH + j];
        __syncthreads();

        float h = b1s[j];
        #pragma unroll 8
        for (int i = 0; i < NCH; ++i)
            h += rows[half][i] * W1s[i * NCH + j];   // broadcast + 2-way alias (free)
        h = (h >= 0.0f) ? h : NEG_SLOPE * h;
        red[half][j] = h * W2s[j];
        __syncthreads();

        for (int off = 64; off > 0; off >>= 1) {
            if (j < off) red[half][j] += red[half][j + off];
            __syncthreads();
        }
        if (j == 0) sval[slot] = red[half][0];
        __syncthreads();
    }

    if (t < 64) {
        const int mb = max_b[b];
        float v = (t < NBR && t <= mb) ? (sval[t] + b2[0]) : 0.0f;
        #pragma unroll
        for (int off = 32; off > 0; off >>= 1) v += __shfl_down(v, off);
        if (t == 0) out[b] = v;
    }
}

extern "C" void kernel_launch(void* const* d_in, const int* in_sizes, int n_in,
                              void* d_out, int out_size, void* d_ws, size_t ws_size,
                              hipStream_t stream) {
    const float* node_embed = (const float*)d_in[0];
    const int*   batch      = (const int*)d_in[1];
    const int*   branch     = (const int*)d_in[2];
    const float* W1         = (const float*)d_in[3];
    const float* b1         = (const float*)d_in[4];
    const float* W2         = (const float*)d_in[5];
    const float* b2         = (const float*)d_in[6];
    float*       out        = (float*)d_out;

    const int n_nodes = in_sizes[0] / NCH;   // 2,000,000

    float* branch_embed = (float*)d_ws;
    int*   max_b = (int*)((char*)d_ws + (size_t)NGR * NBR * NCH * sizeof(float));

    // accumulators must be re-initialized every call (graph replays)
    hipMemsetAsync(branch_embed, 0, (size_t)NGR * NBR * NCH * sizeof(float), stream);
    hipMemsetAsync(max_b, 0x80, NGR * sizeof(int), stream);  // very negative sentinel

    const int grid1 = (n_nodes + CHUNK - 1) / CHUNK;
    scatter_kernel<<<grid1, 256, 0, stream>>>(node_embed, batch, branch,
                                              branch_embed, max_b, n_nodes);
    mlp_kernel<<<NGR, 256, 0, stream>>>(branch_embed, max_b, W1, b1, W2, b2, out);
}

// Round 3
// 250.326 us; speedup vs baseline: 5.5853x; 5.5853x over previous
//
#include <hip/hip_runtime.h>

#define NCH 128      // channels C
#define NGR 256      // graphs B
#define NBR 32       // branches K
#define NEG_SLOPE 0.01f

constexpr int BLK = 1024;   // 16 waves per block, one block per graph
constexpr int SCH = 4096;   // staging chunk (nodes)

// -------- Phase 1: one block per graph; zero atomics in the hot path.
__global__ __launch_bounds__(1024) void scatter_kernel(
    const float* __restrict__ node_embed,   // [N, C]
    const int*   __restrict__ batch,        // [N] sorted
    const int*   __restrict__ branch,       // [N] in [0,K)
    float*       __restrict__ branch_embed, // [B*K, C] (fully overwritten)
    int*         __restrict__ max_b,        // [B]     (fully overwritten)
    int n_nodes)
{
    __shared__ unsigned short sbr[SCH];    // branch id per staged node
    __shared__ unsigned short perm[SCH];   // node indices bucketed by slot
    __shared__ int hist[NBR];
    __shared__ int basec[NBR + 1];
    __shared__ int cur[NBR];
    __shared__ int seg0s, seg1s;
    __shared__ int wmax[BLK / 64];

    const int t    = threadIdx.x;
    const int g    = blockIdx.x;
    const int wave = t >> 6;
    const int lane = t & 63;

    // segment bounds of graph g in sorted batch (thread 0, ~2x21 dependent loads)
    if (t == 0) {
        int lo = 0, hi = n_nodes;
        while (lo < hi) { int mid = (lo + hi) >> 1; if (batch[mid] < g)     lo = mid + 1; else hi = mid; }
        seg0s = lo;
        hi = n_nodes;   // lo already >= lower bound of g+1's search range
        while (lo < hi) { int mid = (lo + hi) >> 1; if (batch[mid] < g + 1) lo = mid + 1; else hi = mid; }
        seg1s = lo;
    }
    __syncthreads();
    const int s0 = seg0s, s1 = seg1s;

    // wave w exclusively owns slots 2w and 2w+1; lane owns channels {2*lane, 2*lane+1}
    float a00 = 0.f, a01 = 0.f;   // slot 2w
    float a10 = 0.f, a11 = 0.f;   // slot 2w+1
    int mymax = -1;

    const float2* ne2 = (const float2*)node_embed;

    for (int c0 = s0; c0 < s1; c0 += SCH) {
        const int clen = min(s1 - c0, SCH);

        if (t < NBR) hist[t] = 0;
        __syncthreads();

        // stage branch ids + histogram
        for (int i = t; i < clen; i += BLK) {
            const int br = branch[c0 + i];
            sbr[i] = (unsigned short)br;
            atomicAdd(&hist[br], 1);
            mymax = max(mymax, br);
        }
        __syncthreads();

        // exclusive prefix scan over 32 counters (wave 0)
        if (wave == 0 && lane < NBR) {
            const int v = hist[lane];
            int acc = v;
            #pragma unroll
            for (int off = 1; off < NBR; off <<= 1) {
                const int o = __shfl_up(acc, off);
                if (lane >= off) acc += o;
            }
            basec[lane] = acc - v;
            cur[lane]   = acc - v;
            if (lane == NBR - 1) basec[NBR] = acc;
        }
        __syncthreads();

        // bucket node indices by slot
        for (int i = t; i < clen; i += BLK) {
            const int pos = atomicAdd(&cur[sbr[i]], 1);
            perm[pos] = (unsigned short)i;
        }
        __syncthreads();

        // accumulate owned slots in registers; 8 independent 512B row-loads in flight
        #define ACCUM_SLOT(S, AX, AY)                                                   \
        {                                                                               \
            int i = basec[S];                                                           \
            const int e = basec[(S) + 1];                                               \
            for (; i + 8 <= e; i += 8) {                                                \
                int n[8];                                                               \
                _Pragma("unroll")                                                       \
                for (int u = 0; u < 8; ++u) n[u] = c0 + perm[i + u];                    \
                float2 v[8];                                                            \
                _Pragma("unroll")                                                       \
                for (int u = 0; u < 8; ++u) v[u] = ne2[(size_t)n[u] * (NCH/2) + lane];  \
                _Pragma("unroll")                                                       \
                for (int u = 0; u < 8; ++u) { AX += v[u].x; AY += v[u].y; }             \
            }                                                                           \
            for (; i < e; ++i) {                                                        \
                const float2 v = ne2[(size_t)(c0 + perm[i]) * (NCH/2) + lane];          \
                AX += v.x; AY += v.y;                                                   \
            }                                                                           \
        }

        ACCUM_SLOT(wave * 2,     a00, a01)
        ACCUM_SLOT(wave * 2 + 1, a10, a11)
        #undef ACCUM_SLOT

        __syncthreads();   // protect sbr/perm before next chunk's staging
    }

    // non-atomic write-out: wave w writes rows g*32+2w, g*32+2w+1
    float2* be2 = (float2*)branch_embed;
    be2[((size_t)g * NBR + wave * 2    ) * (NCH/2) + lane] = make_float2(a00, a01);
    be2[((size_t)g * NBR + wave * 2 + 1) * (NCH/2) + lane] = make_float2(a10, a11);

    // per-graph branch max (non-atomic final store)
    #pragma unroll
    for (int off = 32; off > 0; off >>= 1) mymax = max(mymax, __shfl_down(mymax, off));
    if (lane == 0) wmax[wave] = mymax;
    __syncthreads();
    if (t == 0) {
        int m = wmax[0];
        #pragma unroll
        for (int i = 1; i < BLK / 64; ++i) m = max(m, wmax[i]);
        max_b[g] = m;
    }
}

// -------- Phase 2: per-slot MLP + masked per-graph sum
__global__ __launch_bounds__(256) void mlp_kernel(
    const float* __restrict__ branch_embed, // [B*K, C]
    const int*   __restrict__ max_b,        // [B]
    const float* __restrict__ W1,           // [C, C] row-major
    const float* __restrict__ b1,           // [C]
    const float* __restrict__ W2,           // [C]
    const float* __restrict__ b2,           // [1]
    float*       __restrict__ out)          // [B]
{
    __shared__ float W1s[NCH * NCH];        // 64 KB
    __shared__ float b1s[NCH], W2s[NCH];
    __shared__ float rows[2][NCH];
    __shared__ float red[2][NCH];
    __shared__ float sval[NBR];

    const int t = threadIdx.x;
    const int b = blockIdx.x;

    for (int i = t; i < NCH * NCH / 4; i += 256)
        ((float4*)W1s)[i] = ((const float4*)W1)[i];
    if (t < NCH) { b1s[t] = b1[t]; W2s[t] = W2[t]; }
    __syncthreads();

    const int half = t >> 7;
    const int j    = t & 127;

    for (int k0 = 0; k0 < NBR; k0 += 2) {
        const int slot = k0 + half;
        rows[half][j] = branch_embed[((size_t)b * NBR + slot) * NCH + j];
        __syncthreads();

        float h = b1s[j];
        #pragma unroll 8
        for (int i = 0; i < NCH; ++i)
            h += rows[half][i] * W1s[i * NCH + j];
        h = (h >= 0.0f) ? h : NEG_SLOPE * h;
        red[half][j] = h * W2s[j];
        __syncthreads();

        for (int off = 64; off > 0; off >>= 1) {
            if (j < off) red[half][j] += red[half][j + off];
            __syncthreads();
        }
        if (j == 0) sval[slot] = red[half][0];
        __syncthreads();
    }

    if (t < 64) {
        const int mb = max_b[b];
        float v = (t < NBR && t <= mb) ? (sval[t] + b2[0]) : 0.0f;
        #pragma unroll
        for (int off = 32; off > 0; off >>= 1) v += __shfl_down(v, off);
        if (t == 0) out[b] = v;
    }
}

extern "C" void kernel_launch(void* const* d_in, const int* in_sizes, int n_in,
                              void* d_out, int out_size, void* d_ws, size_t ws_size,
                              hipStream_t stream) {
    const float* node_embed = (const float*)d_in[0];
    const int*   batch      = (const int*)d_in[1];
    const int*   branch     = (const int*)d_in[2];
    const float* W1         = (const float*)d_in[3];
    const float* b1         = (const float*)d_in[4];
    const float* W2         = (const float*)d_in[5];
    const float* b2         = (const float*)d_in[6];
    float*       out        = (float*)d_out;

    const int n_nodes = in_sizes[0] / NCH;   // 2,000,000

    float* branch_embed = (float*)d_ws;
    int*   max_b = (int*)((char*)d_ws + (size_t)NGR * NBR * NCH * sizeof(float));

    // no memsets needed: both buffers fully overwritten non-atomically every call
    scatter_kernel<<<NGR, BLK, 0, stream>>>(node_embed, batch, branch,
                                            branch_embed, max_b, n_nodes);
    mlp_kernel<<<NGR, 256, 0, stream>>>(branch_embed, max_b, W1, b1, W2, b2, out);
}

// Round 4
// 246.109 us; speedup vs baseline: 5.6810x; 1.0171x over previous
//
#include <hip/hip_runtime.h>

#define NCH 128      // channels C
#define NGR 256      // graphs B
#define NBR 32       // branches K
#define NEG_SLOPE 0.01f

typedef __attribute__((ext_vector_type(8))) short bf16x8;   // MFMA A/B operand (4 VGPRs)
typedef __attribute__((ext_vector_type(4))) float f32x4;    // MFMA C/D (16x16)

constexpr int TROWS = 128;   // nodes per LDS tile (4 K-groups of 32)

__device__ inline unsigned short f32_bf16(float x) {        // RTNE truncate
    unsigned u = __float_as_uint(x);
    return (unsigned short)((u + 0x7FFFu + ((u >> 16) & 1u)) >> 16);
}
__device__ inline float bf16_f32(unsigned short h) {
    return __uint_as_float(((unsigned)h) << 16);
}

// -------- Phase 1: streaming onehot-MFMA segment-sum. One block per graph.
__global__ __launch_bounds__(1024) void scatter_mfma(
    const float* __restrict__ node_embed,   // [N, C]
    const int*   __restrict__ batch,        // [N] sorted
    const int*   __restrict__ branch,       // [N] in [0,K)
    float*       __restrict__ branch_embed, // [B*K, C] fully overwritten
    int*         __restrict__ max_b,        // [B]      fully overwritten
    int n_nodes)
{
    __shared__ float buf[2][TROWS][NCH] __attribute__((aligned(16)));  // 128 KB dbuf
    __shared__ unsigned short sbr[2][TROWS] __attribute__((aligned(16)));
    __shared__ int seg_s[2];
    __shared__ int wm[2];

    const int t    = threadIdx.x;
    const int g    = blockIdx.x;
    const int wave = t >> 6;
    const int lane = t & 63;
    const int c    = wave >> 1;      // channel tile 0..7 (16 ch each)
    const int p    = wave & 1;       // K-group parity

    // segment bounds of graph g (batch is sorted)
    if (t < 2) {
        const int target = g + t;
        int lo = 0, hi = n_nodes;
        while (lo < hi) { int mid = (lo + hi) >> 1; if (batch[mid] < target) lo = mid + 1; else hi = mid; }
        seg_s[t] = lo;
    }
    __syncthreads();
    const int s0 = seg_s[0], s1 = seg_s[1];
    const int nt = (s1 - s0 + TROWS - 1) / TROWS;

    // contiguous global -> LDS stage of one 64KB tile (16 waves x 4 x 1KB)
    auto stage_data = [&](int c0n, int nb) {
        #pragma unroll
        for (int u = 0; u < 4; ++u) {
            const int koff = (u * 16 + wave) * 1024;                 // byte offset in tile
            const size_t lanebyte = (size_t)koff + (size_t)lane * 16;
            const int rowg = c0n + (int)(lanebyte >> 9);             // global node row
            const char* src = (const char*)node_embed + (((size_t)c0n << 9) + lanebyte);
            if (rowg >= s1)                                          // tail clamp: safe row, A=0 kills it
                src = (const char*)node_embed + ((size_t)s0 << 9);
            __builtin_amdgcn_global_load_lds(
                (const __attribute__((address_space(1))) void*)src,
                (__attribute__((address_space(3))) void*)((char*)&buf[nb][0][0] + koff),
                16, 0, 0);
        }
    };

    f32x4 acc0 = {0.f, 0.f, 0.f, 0.f};   // slots 0..15  x ch-tile c
    f32x4 acc1 = {0.f, 0.f, 0.f, 0.f};   // slots 16..31 x ch-tile c
    int mymax = -1;

    // prologue: tile 0
    if (nt > 0) {
        stage_data(s0, 0);
        if (t < TROWS) {
            const int i = s0 + t;
            unsigned short mm = 0xFFFFu;
            if (i < s1) { const int br = branch[i]; mymax = max(mymax, br); mm = (unsigned short)br; }
            sbr[0][t] = mm;
        }
        __syncthreads();   // drains global_load_lds (vmcnt) + lds writes
    }

    const int gq = lane >> 4;     // 0..3 (K sub-group)
    const int m  = lane & 15;     // A row (slot) / B col (ch) / D col

    for (int ti = 0; ti < nt; ++ti) {
        const int cb = ti & 1;
        const bool pre = (ti + 1 < nt);
        unsigned short nxt = 0xFFFFu;
        if (pre) {
            const int c0n = s0 + (ti + 1) * TROWS;
            stage_data(c0n, cb ^ 1);                       // async prefetch
            if (t < TROWS) {
                const int i = c0n + t;
                if (i < s1) { const int br = branch[i]; mymax = max(mymax, br); nxt = (unsigned short)br; }
            }
        }

        // compute this tile: 2 K-groups for this parity
        #pragma unroll
        for (int kk = 0; kk < 2; ++kk) {
            const int rb = (p + 2 * kk) * 32;              // K-group row base
            const int4 idraw = *(const int4*)((const char*)&sbr[cb][0] + rb * 2 + gq * 16);
            unsigned idv[8];
            idv[0] = (unsigned)idraw.x & 0xFFFFu; idv[1] = (unsigned)idraw.x >> 16;
            idv[2] = (unsigned)idraw.y & 0xFFFFu; idv[3] = (unsigned)idraw.y >> 16;
            idv[4] = (unsigned)idraw.z & 0xFFFFu; idv[5] = (unsigned)idraw.z >> 16;
            idv[6] = (unsigned)idraw.w & 0xFFFFu; idv[7] = (unsigned)idraw.w >> 16;

            bf16x8 a0, a1, bhi, blo;
            #pragma unroll
            for (int j = 0; j < 8; ++j) {
                const float v = buf[cb][rb + gq * 8 + j][c * 16 + m];
                const unsigned short h = f32_bf16(v);
                const unsigned short l = f32_bf16(v - bf16_f32(h));
                bhi[j] = (short)h;
                blo[j] = (short)l;
                a0[j] = (idv[j] == (unsigned)m)        ? (short)0x3F80 : (short)0;
                a1[j] = (idv[j] == (unsigned)(m + 16)) ? (short)0x3F80 : (short)0;
            }
            acc0 = __builtin_amdgcn_mfma_f32_16x16x32_bf16(a0, bhi, acc0, 0, 0, 0);
            acc0 = __builtin_amdgcn_mfma_f32_16x16x32_bf16(a0, blo, acc0, 0, 0, 0);
            acc1 = __builtin_amdgcn_mfma_f32_16x16x32_bf16(a1, bhi, acc1, 0, 0, 0);
            acc1 = __builtin_amdgcn_mfma_f32_16x16x32_bf16(a1, blo, acc1, 0, 0, 0);
        }

        if (pre && t < TROWS) sbr[cb ^ 1][t] = nxt;        // late LDS write (T14 split)
        __syncthreads();                                   // drains prefetch vmcnt + lds
    }

    // cross-parity reduce through LDS (alias onto buf), then non-atomic writeout
    __syncthreads();
    float* red = &buf[0][0][0];
    if (p == 1) {
        float* dst = red + ((size_t)c * 64 + lane) * 8;
        #pragma unroll
        for (int r = 0; r < 4; ++r) { dst[r] = acc0[r]; dst[4 + r] = acc1[r]; }
    }
    __syncthreads();
    if (p == 0) {
        const float* src = red + ((size_t)c * 64 + lane) * 8;
        #pragma unroll
        for (int r = 0; r < 4; ++r) { acc0[r] += src[r]; acc1[r] += src[4 + r]; }
        const int sr = gq * 4;                             // D row = (lane>>4)*4 + reg  [m89]
        float* be = branch_embed + (size_t)g * NBR * NCH + (size_t)c * 16 + m;
        #pragma unroll
        for (int r = 0; r < 4; ++r) {
            be[(sr + r) * NCH]      = acc0[r];             // slots 0..15
            be[(16 + sr + r) * NCH] = acc1[r];             // slots 16..31
        }
    }

    // per-graph branch max (threads 0..127 observed all branch ids)
    int v = mymax;
    #pragma unroll
    for (int off = 32; off > 0; off >>= 1) v = max(v, __shfl_down(v, off));
    if (wave < 2 && lane == 0) wm[wave] = v;
    __syncthreads();
    if (t == 0) max_b[g] = max(wm[0], wm[1]);
}

// -------- Phase 2: per-slot MLP + masked per-graph sum (unchanged, verified)
__global__ __launch_bounds__(256) void mlp_kernel(
    const float* __restrict__ branch_embed, // [B*K, C]
    const int*   __restrict__ max_b,        // [B]
    const float* __restrict__ W1,           // [C, C] row-major
    const float* __restrict__ b1,           // [C]
    const float* __restrict__ W2,           // [C]
    const float* __restrict__ b2,           // [1]
    float*       __restrict__ out)          // [B]
{
    __shared__ float W1s[NCH * NCH];
    __shared__ float b1s[NCH], W2s[NCH];
    __shared__ float rows[2][NCH];
    __shared__ float red[2][NCH];
    __shared__ float sval[NBR];

    const int t = threadIdx.x;
    const int b = blockIdx.x;

    for (int i = t; i < NCH * NCH / 4; i += 256)
        ((float4*)W1s)[i] = ((const float4*)W1)[i];
    if (t < NCH) { b1s[t] = b1[t]; W2s[t] = W2[t]; }
    __syncthreads();

    const int half = t >> 7;
    const int j    = t & 127;

    for (int k0 = 0; k0 < NBR; k0 += 2) {
        const int slot = k0 + half;
        rows[half][j] = branch_embed[((size_t)b * NBR + slot) * NCH + j];
        __syncthreads();

        float h = b1s[j];
        #pragma unroll 8
        for (int i = 0; i < NCH; ++i)
            h += rows[half][i] * W1s[i * NCH + j];
        h = (h >= 0.0f) ? h : NEG_SLOPE * h;
        red[half][j] = h * W2s[j];
        __syncthreads();

        for (int off = 64; off > 0; off >>= 1) {
            if (j < off) red[half][j] += red[half][j + off];
            __syncthreads();
        }
        if (j == 0) sval[slot] = red[half][0];
        __syncthreads();
    }

    if (t < 64) {
        const int mb = max_b[b];
        float v = (t < NBR && t <= mb) ? (sval[t] + b2[0]) : 0.0f;
        #pragma unroll
        for (int off = 32; off > 0; off >>= 1) v += __shfl_down(v, off);
        if (t == 0) out[b] = v;
    }
}

extern "C" void kernel_launch(void* const* d_in, const int* in_sizes, int n_in,
                              void* d_out, int out_size, void* d_ws, size_t ws_size,
                              hipStream_t stream) {
    const float* node_embed = (const float*)d_in[0];
    const int*   batch      = (const int*)d_in[1];
    const int*   branch     = (const int*)d_in[2];
    const float* W1         = (const float*)d_in[3];
    const float* b1         = (const float*)d_in[4];
    const float* W2         = (const float*)d_in[5];
    const float* b2         = (const float*)d_in[6];
    float*       out        = (float*)d_out;

    const int n_nodes = in_sizes[0] / NCH;   // 2,000,000

    float* branch_embed = (float*)d_ws;
    int*   max_b = (int*)((char*)d_ws + (size_t)NGR * NBR * NCH * sizeof(float));

    // both workspace buffers fully overwritten non-atomically every call
    scatter_mfma<<<NGR, 1024, 0, stream>>>(node_embed, batch, branch,
                                           branch_embed, max_b, n_nodes);
    mlp_kernel<<<NGR, 256, 0, stream>>>(branch_embed, max_b, W1, b1, W2, b2, out);
}

// Round 5
// 235.855 us; speedup vs baseline: 5.9280x; 1.0435x over previous
//
#include <hip/hip_runtime.h>

#define NCH 128      // channels C
#define NGR 256      // graphs B
#define NBR 32       // branches K
#define NEG_SLOPE 0.01f

typedef __attribute__((ext_vector_type(8))) short bf16x8;   // MFMA A/B operand (4 VGPRs)
typedef __attribute__((ext_vector_type(4))) float f32x4;    // MFMA C/D (16x16)

constexpr int TROWS = 128;   // nodes per LDS tile (4 K-groups of 32)

__device__ inline unsigned short rtne_bf16(float x) {
    unsigned u = __float_as_uint(x);
    return (unsigned short)((u + 0x7FFFu + ((u >> 16) & 1u)) >> 16);
}

// one 16-slot x 16-ch MFMA step over both K-parities of this wave
template <bool TAIL>
__device__ inline void compute_tile(
    const float (*__restrict__ buf)[NCH], const int* __restrict__ sbr, int rem,
    int p, int c, int gq, int m,
    f32x4& acc0, f32x4& acc1, int& mymax)
{
    #pragma unroll
    for (int kk = 0; kk < 2; ++kk) {
        const int rb = (p + 2 * kk) * 32 + gq * 8;   // this lane's 8 K-rows
        int idv[8];
        {
            const int4 i0 = *(const int4*)&sbr[rb];
            const int4 i1 = *(const int4*)&sbr[rb + 4];
            idv[0] = i0.x; idv[1] = i0.y; idv[2] = i0.z; idv[3] = i0.w;
            idv[4] = i1.x; idv[5] = i1.y; idv[6] = i1.z; idv[7] = i1.w;
        }
        bf16x8 a0, a1, bhi, blo;
        #pragma unroll
        for (int j = 0; j < 8; ++j) {
            const float v = buf[rb + j][c * 16 + m];
            const unsigned u = __float_as_uint(v);
            const unsigned short h = (unsigned short)(u >> 16);        // truncated hi
            const float hf = __uint_as_float(u & 0xFFFF0000u);
            const unsigned short l = rtne_bf16(v - hf);                // exact-ish residual
            bhi[j] = (short)h;
            blo[j] = (short)l;
            bool val = true;
            if (TAIL) val = (rb + j) < rem;
            a0[j] = (val && idv[j] == m)      ? (short)0x3F80 : (short)0;
            a1[j] = (val && idv[j] == m + 16) ? (short)0x3F80 : (short)0;
            if (TAIL) { if (val) mymax = max(mymax, idv[j]); }
            else      mymax = max(mymax, idv[j]);
        }
        acc0 = __builtin_amdgcn_mfma_f32_16x16x32_bf16(a0, bhi, acc0, 0, 0, 0);
        acc0 = __builtin_amdgcn_mfma_f32_16x16x32_bf16(a0, blo, acc0, 0, 0, 0);
        acc1 = __builtin_amdgcn_mfma_f32_16x16x32_bf16(a1, bhi, acc1, 0, 0, 0);
        acc1 = __builtin_amdgcn_mfma_f32_16x16x32_bf16(a1, blo, acc1, 0, 0, 0);
    }
}

// -------- Phase 1: streaming onehot-MFMA segment-sum, counted-vmcnt pipeline.
__global__ __launch_bounds__(1024) void scatter_mfma(
    const float* __restrict__ node_embed,   // [N, C]
    const int*   __restrict__ batch,        // [N] sorted
    const int*   __restrict__ branch,       // [N] in [0,K)
    float*       __restrict__ branch_embed, // [B*K, C] fully overwritten
    int*         __restrict__ max_b,        // [B]      fully overwritten
    int n_nodes)
{
    __shared__ float buf[2][TROWS][NCH] __attribute__((aligned(16)));  // 128 KB dbuf
    __shared__ int   sbr_i[2][TROWS]    __attribute__((aligned(16))); // branch ids (int)
    __shared__ int   seg_s[2];
    __shared__ int   wm[16];

    const int t    = threadIdx.x;
    const int g    = blockIdx.x;
    const int wave = t >> 6;
    const int lane = t & 63;
    const int c    = wave >> 1;      // channel tile 0..7
    const int p    = wave & 1;       // K-group parity
    const int gq   = lane >> 4;
    const int m    = lane & 15;

    if (t < 2) {
        const int target = g + t;
        int lo = 0, hi = n_nodes;
        while (lo < hi) { int mid = (lo + hi) >> 1; if (batch[mid] < target) lo = mid + 1; else hi = mid; }
        seg_s[t] = lo;
    }
    __syncthreads();
    const int s0 = seg_s[0], s1 = seg_s[1];
    const int nt = (s1 - s0 + TROWS - 1) / TROWS;

    // stage one tile: 64 KB data (16 waves x 4 x 1KB) + 512 B branch ids (wave 0)
    auto stage = [&](int ti2) {
        const int c0n = s0 + ti2 * TROWS;
        const int nb  = ti2 & 1;
        #pragma unroll
        for (int u = 0; u < 4; ++u) {
            const int koff = (u * 16 + wave) * 1024;
            const size_t lanebyte = (size_t)koff + (size_t)lane * 16;
            const int rowg = c0n + (int)(lanebyte >> 9);
            const char* src = (const char*)node_embed + (((size_t)c0n << 9) + lanebyte);
            if (rowg >= s1)                          // tail clamp: real floats, A=0 masks
                src = (const char*)node_embed + ((size_t)s0 << 9);
            __builtin_amdgcn_global_load_lds(
                (const __attribute__((address_space(1))) void*)src,
                (__attribute__((address_space(3))) void*)((char*)&buf[nb][0][0] + koff),
                16, 0, 0);
        }
        if (wave == 0) {                             // branch ids -> LDS, no reg roundtrip
            const int i0 = min(c0n + lane,      n_nodes - 1);
            const int i1 = min(c0n + 64 + lane, n_nodes - 1);
            __builtin_amdgcn_global_load_lds(
                (const __attribute__((address_space(1))) void*)(branch + i0),
                (__attribute__((address_space(3))) void*)((char*)&sbr_i[nb][0]), 4, 0, 0);
            __builtin_amdgcn_global_load_lds(
                (const __attribute__((address_space(1))) void*)(branch + i1),
                (__attribute__((address_space(3))) void*)((char*)&sbr_i[nb][0] + 256), 4, 0, 0);
        }
    };

    f32x4 acc0 = {0.f, 0.f, 0.f, 0.f};
    f32x4 acc1 = {0.f, 0.f, 0.f, 0.f};
    int mymax = -1;

    if (nt > 0) {
        stage(0);
        if (nt > 1) stage(1);
        // wait tile 0 only (keep tile 1 in flight)
        if (nt > 1) {
            if (wave == 0) asm volatile("s_waitcnt vmcnt(6)" ::: "memory");
            else           asm volatile("s_waitcnt vmcnt(4)" ::: "memory");
        } else {
            asm volatile("s_waitcnt vmcnt(0)" ::: "memory");
        }
        __builtin_amdgcn_s_barrier();
        __builtin_amdgcn_sched_barrier(0);

        for (int ti = 0; ti < nt; ++ti) {
            const int cb = ti & 1;
            if (ti == nt - 1)
                compute_tile<true >(buf[cb], sbr_i[cb], s1 - (s0 + ti * TROWS),
                                    p, c, gq, m, acc0, acc1, mymax);
            else
                compute_tile<false>(buf[cb], sbr_i[cb], 0,
                                    p, c, gq, m, acc0, acc1, mymax);

            __builtin_amdgcn_s_barrier();            // all waves done reading buf[cb]
            __builtin_amdgcn_sched_barrier(0);

            const bool more = (ti + 2 < nt);
            if (more) stage(ti + 2);                 // refill buf[cb] asynchronously
            if (ti + 1 < nt) {
                // wait tile ti+1 landed; leave tile ti+2 (if any) in flight
                if (more) {
                    if (wave == 0) asm volatile("s_waitcnt vmcnt(6)" ::: "memory");
                    else           asm volatile("s_waitcnt vmcnt(4)" ::: "memory");
                } else {
                    asm volatile("s_waitcnt vmcnt(0)" ::: "memory");
                }
                __builtin_amdgcn_s_barrier();
                __builtin_amdgcn_sched_barrier(0);
            }
        }
    }

    // cross-parity reduce through LDS (alias onto buf), then non-atomic writeout
    __syncthreads();
    float* red = &buf[0][0][0];
    if (p == 1) {
        float* dst = red + ((size_t)c * 64 + lane) * 8;
        #pragma unroll
        for (int r = 0; r < 4; ++r) { dst[r] = acc0[r]; dst[4 + r] = acc1[r]; }
    }
    __syncthreads();
    if (p == 0) {
        const float* src = red + ((size_t)c * 64 + lane) * 8;
        #pragma unroll
        for (int r = 0; r < 4; ++r) { acc0[r] += src[r]; acc1[r] += src[4 + r]; }
        const int sr = gq * 4;                       // D row = (lane>>4)*4 + reg  [m89]
        float* be = branch_embed + (size_t)g * NBR * NCH + (size_t)c * 16 + m;
        #pragma unroll
        for (int r = 0; r < 4; ++r) {
            be[(sr + r) * NCH]      = acc0[r];       // slots 0..15
            be[(16 + sr + r) * NCH] = acc1[r];       // slots 16..31
        }
    }

    // per-graph branch max (all waves observed all rows across parities/kk/gq)
    int v = mymax;
    #pragma unroll
    for (int off = 32; off > 0; off >>= 1) v = max(v, __shfl_down(v, off));
    if (lane == 0) wm[wave] = v;
    __syncthreads();
    if (t == 0) {
        int mb = wm[0];
        #pragma unroll
        for (int i = 1; i < 16; ++i) mb = max(mb, wm[i]);
        max_b[g] = mb;
    }
}

// -------- Phase 2: per-slot MLP + masked per-graph sum (verified)
__global__ __launch_bounds__(256) void mlp_kernel(
    const float* __restrict__ branch_embed, // [B*K, C]
    const int*   __restrict__ max_b,        // [B]
    const float* __restrict__ W1,           // [C, C] row-major
    const float* __restrict__ b1,           // [C]
    const float* __restrict__ W2,           // [C]
    const float* __restrict__ b2,           // [1]
    float*       __restrict__ out)          // [B]
{
    __shared__ float W1s[NCH * NCH];
    __shared__ float b1s[NCH], W2s[NCH];
    __shared__ float rows[2][NCH];
    __shared__ float red[2][NCH];
    __shared__ float sval[NBR];

    const int t = threadIdx.x;
    const int b = blockIdx.x;

    for (int i = t; i < NCH * NCH / 4; i += 256)
        ((float4*)W1s)[i] = ((const float4*)W1)[i];
    if (t < NCH) { b1s[t] = b1[t]; W2s[t] = W2[t]; }
    __syncthreads();

    const int half = t >> 7;
    const int j    = t & 127;

    for (int k0 = 0; k0 < NBR; k0 += 2) {
        const int slot = k0 + half;
        rows[half][j] = branch_embed[((size_t)b * NBR + slot) * NCH + j];
        __syncthreads();

        float h = b1s[j];
        #pragma unroll 8
        for (int i = 0; i < NCH; ++i)
            h += rows[half][i] * W1s[i * NCH + j];
        h = (h >= 0.0f) ? h : NEG_SLOPE * h;
        red[half][j] = h * W2s[j];
        __syncthreads();

        for (int off = 64; off > 0; off >>= 1) {
            if (j < off) red[half][j] += red[half][j + off];
            __syncthreads();
        }
        if (j == 0) sval[slot] = red[half][0];
        __syncthreads();
    }

    if (t < 64) {
        const int mb = max_b[b];
        float v = (t < NBR && t <= mb) ? (sval[t] + b2[0]) : 0.0f;
        #pragma unroll
        for (int off = 32; off > 0; off >>= 1) v += __shfl_down(v, off);
        if (t == 0) out[b] = v;
    }
}

extern "C" void kernel_launch(void* const* d_in, const int* in_sizes, int n_in,
                              void* d_out, int out_size, void* d_ws, size_t ws_size,
                              hipStream_t stream) {
    const float* node_embed = (const float*)d_in[0];
    const int*   batch      = (const int*)d_in[1];
    const int*   branch     = (const int*)d_in[2];
    const float* W1         = (const float*)d_in[3];
    const float* b1         = (const float*)d_in[4];
    const float* W2         = (const float*)d_in[5];
    const float* b2         = (const float*)d_in[6];
    float*       out        = (float*)d_out;

    const int n_nodes = in_sizes[0] / NCH;   // 2,000,000

    float* branch_embed = (float*)d_ws;
    int*   max_b = (int*)((char*)d_ws + (size_t)NGR * NBR * NCH * sizeof(float));

    // both workspace buffers fully overwritten non-atomically every call
    scatter_mfma<<<NGR, 1024, 0, stream>>>(node_embed, batch, branch,
                                           branch_embed, max_b, n_nodes);
    mlp_kernel<<<NGR, 256, 0, stream>>>(branch_embed, max_b, W1, b1, W2, b2, out);
}

// Round 6
// 233.160 us; speedup vs baseline: 5.9965x; 1.0116x over previous
//
#include <hip/hip_runtime.h>

#define NCH 128      // channels C
#define NGR 256      // graphs B
#define NBR 32       // branches K
#define NEG_SLOPE 0.01f

typedef __attribute__((ext_vector_type(8))) short bf16x8;   // MFMA A/B operand
typedef __attribute__((ext_vector_type(4))) float f32x4;    // MFMA C/D (16x16)

constexpr int TROWS = 64;    // nodes per LDS tile (32 KB): 2 K-groups of 32

__device__ inline unsigned short rtne_bf16(float x) {
    unsigned u = __float_as_uint(x);
    return (unsigned short)((u + 0x7FFFu + ((u >> 16) & 1u)) >> 16);
}

// one tile: 2 K-groups x (slots 0-15, 16-31) for this wave's 16-ch tile
template <bool TAIL>
__device__ inline void compute_tile(
    const float (*__restrict__ buf)[NCH], const int* __restrict__ sbr, int rem,
    int c, int gq, int m,
    f32x4& acc0, f32x4& acc1, int& mymax)
{
    #pragma unroll
    for (int kk = 0; kk < 2; ++kk) {
        const int rb = kk * 32 + gq * 8;            // this lane's 8 K-rows
        int idv[8];
        {
            const int4 i0 = *(const int4*)&sbr[rb];
            const int4 i1 = *(const int4*)&sbr[rb + 4];
            idv[0] = i0.x; idv[1] = i0.y; idv[2] = i0.z; idv[3] = i0.w;
            idv[4] = i1.x; idv[5] = i1.y; idv[6] = i1.z; idv[7] = i1.w;
        }
        bf16x8 a0, a1, bhi, blo;
        #pragma unroll
        for (int j = 0; j < 8; ++j) {
            const float v = buf[rb + j][c * 16 + m];
            const unsigned u = __float_as_uint(v);
            const unsigned short h = (unsigned short)(u >> 16);   // truncated hi
            const float hf = __uint_as_float(u & 0xFFFF0000u);
            const unsigned short l = rtne_bf16(v - hf);           // residual
            bhi[j] = (short)h;
            blo[j] = (short)l;
            bool val = true;
            if (TAIL) val = (rb + j) < rem;
            a0[j] = (val && idv[j] == m)      ? (short)0x3F80 : (short)0;
            a1[j] = (val && idv[j] == m + 16) ? (short)0x3F80 : (short)0;
            if (val) mymax = max(mymax, idv[j]);
        }
        acc0 = __builtin_amdgcn_mfma_f32_16x16x32_bf16(a0, bhi, acc0, 0, 0, 0);
        acc0 = __builtin_amdgcn_mfma_f32_16x16x32_bf16(a0, blo, acc0, 0, 0, 0);
        acc1 = __builtin_amdgcn_mfma_f32_16x16x32_bf16(a1, bhi, acc1, 0, 0, 0);
        acc1 = __builtin_amdgcn_mfma_f32_16x16x32_bf16(a1, blo, acc1, 0, 0, 0);
    }
}

// -------- Phase 1: streaming onehot-MFMA segment-sum.
// 512 blocks (2 per graph, half-segment each), 512 threads, 2 blocks/CU.
__global__ __launch_bounds__(512, 4) void scatter_mfma(
    const float* __restrict__ node_embed,   // [N, C]
    const int*   __restrict__ batch,        // [N] sorted
    const int*   __restrict__ branch,       // [N] in [0,K)
    float*       __restrict__ part,         // [2][B*K, C] fully overwritten
    int*         __restrict__ max_b_part,   // [2][B]      fully overwritten
    int n_nodes)
{
    __shared__ float buf[2][TROWS][NCH] __attribute__((aligned(16)));  // 64 KB dbuf
    __shared__ int   sbr_i[2][TROWS]    __attribute__((aligned(16)));
    __shared__ int   seg_s[2];
    __shared__ int   wm[8];

    const int t    = threadIdx.x;
    const int bid  = blockIdx.x;
    const int g    = bid >> 1;
    const int half = bid & 1;
    const int wave = t >> 6;
    const int lane = t & 63;
    const int c    = wave;           // channel tile 0..7 (16 ch each)
    const int gq   = lane >> 4;
    const int m    = lane & 15;

    if (t < 2) {
        const int target = g + t;
        int lo = 0, hi = n_nodes;
        while (lo < hi) { int mid = (lo + hi) >> 1; if (batch[mid] < target) lo = mid + 1; else hi = mid; }
        seg_s[t] = lo;
    }
    __syncthreads();
    const int s0 = seg_s[0], s1 = seg_s[1];
    const int nt_tot = (s1 - s0 + TROWS - 1) / TROWS;
    const int ntA    = (nt_tot + 1) >> 1;                     // tiles in half 0
    const int sa     = half ? s0 + ntA * TROWS : s0;          // this half's range
    const int nt     = half ? nt_tot - ntA : ntA;

    // stage one 32KB tile (8 waves x 4 x 1KB) + 256B branch ids (wave 0)
    auto stage = [&](int ti2) {
        const int c0n = sa + ti2 * TROWS;
        const int nb  = ti2 & 1;
        #pragma unroll
        for (int u = 0; u < 4; ++u) {
            const int koff = (u * 8 + wave) * 1024;
            const size_t lanebyte = (size_t)koff + (size_t)lane * 16;
            const int rowg = c0n + (int)(lanebyte >> 9);
            const char* src = (const char*)node_embed + (((size_t)c0n << 9) + lanebyte);
            if (rowg >= s1)                     // tail clamp: valid memory, masked in compute
                src = (const char*)node_embed;
            __builtin_amdgcn_global_load_lds(
                (const __attribute__((address_space(1))) void*)src,
                (__attribute__((address_space(3))) void*)((char*)&buf[nb][0][0] + koff),
                16, 0, 0);
        }
        if (wave == 0) {
            const int i0 = min(c0n + lane, n_nodes - 1);
            __builtin_amdgcn_global_load_lds(
                (const __attribute__((address_space(1))) void*)(branch + i0),
                (__attribute__((address_space(3))) void*)((char*)&sbr_i[nb][0]), 4, 0, 0);
        }
    };

    f32x4 acc0 = {0.f, 0.f, 0.f, 0.f};
    f32x4 acc1 = {0.f, 0.f, 0.f, 0.f};
    int mymax = -1;

    if (nt > 0) {
        stage(0);
        if (nt > 1) stage(1);
        if (nt > 1) {
            if (wave == 0) asm volatile("s_waitcnt vmcnt(5)" ::: "memory");
            else           asm volatile("s_waitcnt vmcnt(4)" ::: "memory");
        } else {
            asm volatile("s_waitcnt vmcnt(0)" ::: "memory");
        }
        __builtin_amdgcn_s_barrier();
        __builtin_amdgcn_sched_barrier(0);

        for (int ti = 0; ti < nt; ++ti) {
            const int cb = ti & 1;
            if (ti == nt - 1)
                compute_tile<true >(buf[cb], sbr_i[cb], s1 - (sa + ti * TROWS),
                                    c, gq, m, acc0, acc1, mymax);
            else
                compute_tile<false>(buf[cb], sbr_i[cb], 0,
                                    c, gq, m, acc0, acc1, mymax);

            __builtin_amdgcn_s_barrier();            // all waves done reading buf[cb]
            __builtin_amdgcn_sched_barrier(0);

            const bool more = (ti + 2 < nt);
            if (more) stage(ti + 2);                 // refill buf[cb] asynchronously
            if (ti + 1 < nt) {
                if (more) {
                    if (wave == 0) asm volatile("s_waitcnt vmcnt(5)" ::: "memory");
                    else           asm volatile("s_waitcnt vmcnt(4)" ::: "memory");
                } else {
                    asm volatile("s_waitcnt vmcnt(0)" ::: "memory");
                }
                __builtin_amdgcn_s_barrier();
                __builtin_amdgcn_sched_barrier(0);
            }
        }
    }

    // non-atomic writeout: wave owns its full 16-ch tile (both slot halves)
    {
        const int sr = gq * 4;                       // D row = (lane>>4)*4 + reg  [m89]
        float* be = part + (size_t)half * NGR * NBR * NCH
                  + (size_t)g * NBR * NCH + (size_t)c * 16 + m;
        #pragma unroll
        for (int r = 0; r < 4; ++r) {
            be[(sr + r) * NCH]      = acc0[r];       // slots 0..15
            be[(16 + sr + r) * NCH] = acc1[r];       // slots 16..31
        }
    }

    // per-graph-half branch max
    int v = mymax;
    #pragma unroll
    for (int off = 32; off > 0; off >>= 1) v = max(v, __shfl_down(v, off));
    if (lane == 0) wm[wave] = v;
    __syncthreads();
    if (t == 0) {
        int mb = wm[0];
        #pragma unroll
        for (int i = 1; i < 8; ++i) mb = max(mb, wm[i]);
        max_b_part[half * NGR + g] = mb;
    }
}

// -------- Phase 2: per-slot MLP + masked per-graph sum (sums the 2 partials)
__global__ __launch_bounds__(256) void mlp_kernel(
    const float* __restrict__ part,         // [2][B*K, C]
    const int*   __restrict__ max_b_part,   // [2][B]
    const float* __restrict__ W1,           // [C, C] row-major
    const float* __restrict__ b1,           // [C]
    const float* __restrict__ W2,           // [C]
    const float* __restrict__ b2,           // [1]
    float*       __restrict__ out)          // [B]
{
    __shared__ float W1s[NCH * NCH];
    __shared__ float b1s[NCH], W2s[NCH];
    __shared__ float rows[2][NCH];
    __shared__ float red[2][NCH];
    __shared__ float sval[NBR];

    const int t = threadIdx.x;
    const int b = blockIdx.x;

    for (int i = t; i < NCH * NCH / 4; i += 256)
        ((float4*)W1s)[i] = ((const float4*)W1)[i];
    if (t < NCH) { b1s[t] = b1[t]; W2s[t] = W2[t]; }
    __syncthreads();

    const int half = t >> 7;
    const int j    = t & 127;
    const float* p1 = part + (size_t)NGR * NBR * NCH;

    for (int k0 = 0; k0 < NBR; k0 += 2) {
        const int slot = k0 + half;
        const size_t idx = ((size_t)b * NBR + slot) * NCH + j;
        rows[half][j] = part[idx] + p1[idx];
        __syncthreads();

        float h = b1s[j];
        #pragma unroll 8
        for (int i = 0; i < NCH; ++i)
            h += rows[half][i] * W1s[i * NCH + j];
        h = (h >= 0.0f) ? h : NEG_SLOPE * h;
        red[half][j] = h * W2s[j];
        __syncthreads();

        for (int off = 64; off > 0; off >>= 1) {
            if (j < off) red[half][j] += red[half][j + off];
            __syncthreads();
        }
        if (j == 0) sval[slot] = red[half][0];
        __syncthreads();
    }

    if (t < 64) {
        const int mb = max(max_b_part[b], max_b_part[NGR + b]);
        float v = (t < NBR && t <= mb) ? (sval[t] + b2[0]) : 0.0f;
        #pragma unroll
        for (int off = 32; off > 0; off >>= 1) v += __shfl_down(v, off);
        if (t == 0) out[b] = v;
    }
}

extern "C" void kernel_launch(void* const* d_in, const int* in_sizes, int n_in,
                              void* d_out, int out_size, void* d_ws, size_t ws_size,
                              hipStream_t stream) {
    const float* node_embed = (const float*)d_in[0];
    const int*   batch      = (const int*)d_in[1];
    const int*   branch     = (const int*)d_in[2];
    const float* W1         = (const float*)d_in[3];
    const float* b1         = (const float*)d_in[4];
    const float* W2         = (const float*)d_in[5];
    const float* b2         = (const float*)d_in[6];
    float*       out        = (float*)d_out;

    const int n_nodes = in_sizes[0] / NCH;   // 2,000,000

    float* part = (float*)d_ws;                                   // 2 x 4 MB partials
    int*   max_b_part = (int*)((char*)d_ws + 2 * (size_t)NGR * NBR * NCH * sizeof(float));

    // both workspace buffers fully overwritten non-atomically every call
    scatter_mfma<<<2 * NGR, 512, 0, stream>>>(node_embed, batch, branch,
                                              part, max_b_part, n_nodes);
    mlp_kernel<<<NGR, 256, 0, stream>>>(part, max_b_part, W1, b1, W2, b2, out);
}